// Round 2
// baseline (2231.549 us; speedup 1.0000x reference)
//
#include <hip/hip_runtime.h>

#define NPTS   100000
#define BIGF   3.4e38f
#define NS_ITERS 26
#define NB     64          // persistent-kernel blocks (<= 256 CUs -> co-resident)

// scal[] slots
#define SC_LM   0
#define SC_TRCX 1
#define SC_TRCT 2
#define SC_FROB 3
#define SC_KNN  4
#define SC_REG  5
#define SC_LD   6

// ---- ws layout (float offsets) ----
#define O_MUSUM 0
#define O_SCAL  256
#define O_BAR   272          // int barrier counter (inside zeroed region)
#define O_COVX  1024         // 65536
#define O_TM    66560        // 65536
#define O_COV   132096       // 65536
#define O_G     197632       // 65536
#define O_Y0    263168
#define O_Z0    328704
#define O_Y1    394240
#define O_Z1    459776
#define O_PM    525312
#define O_MUT   590848       // 256
#define O_XSQ   591104       // 100000
#define O_POSTW 691200       // 4096
#define O_POSTI 695296       // int 4096
#define O_CAND  699392       // int 256*32
#define O_TB    707584       // ushort 65536 (32768 floats)
#define O_XB    740352       // ushort 100096*256 (12812288 floats)
#define O_CK    13552640     // float 256*4692
#define O_CI    14753792     // int   256*4692   -> ends 15954944 floats (~64 MB)

#define NCAND   4692         // 782 chunks * 6

typedef __bf16 bfx8 __attribute__((ext_vector_type(8)));
typedef float  fx4  __attribute__((ext_vector_type(4)));

__device__ __forceinline__ ushort f2bf(float f) {
    uint u = __float_as_uint(f);
    u = (u + 0x7FFFu + ((u >> 16) & 1u)) >> 16;   // RNE
    return (ushort)u;
}

// ---------------- zero init (mu_sum, scal, barrier, covX acc) ----------------
__global__ __launch_bounds__(256) void zero_kernel(float* ws) {
    int idx = blockIdx.x * 256 + threadIdx.x;
    if (idx < 66560) ws[idx] = 0.0f;
}

// ---------------- reg: sum(W^2) ----------------
__global__ __launch_bounds__(256) void reg_kernel(const float* __restrict__ W, float* __restrict__ scal) {
    __shared__ float red[256];
    int t = threadIdx.x;
    float s = 0.f;
    int base = blockIdx.x * 1024;
    for (int m = 0; m < 4; ++m) { float w = W[base + m * 256 + t]; s += w * w; }
    red[t] = s;
    __syncthreads();
    for (int s2 = 128; s2 > 0; s2 >>= 1) { if (t < s2) red[t] += red[t + s2]; __syncthreads(); }
    if (t == 0) atomicAdd(&scal[SC_REG], red[0]);
}

// ---------------- X stats + bf16 convert: xsq, mu_sum, Xb ----------------
__global__ __launch_bounds__(256) void statsconv(const float* __restrict__ X,
                                                 float* __restrict__ xsq,
                                                 float* __restrict__ mu_sum,
                                                 ushort* __restrict__ Xb) {
    int w    = threadIdx.x >> 6;
    int lane = threadIdx.x & 63;
    int rbase = blockIdx.x * 1024;
    float cs0 = 0.f, cs1 = 0.f, cs2 = 0.f, cs3 = 0.f;
    for (int m = 0; m < 256; ++m) {
        int r = rbase + w + 4 * m;
        if (r < NPTS) {
            float4 v = *(const float4*)&X[r * 256 + 4 * lane];
            cs0 += v.x; cs1 += v.y; cs2 += v.z; cs3 += v.w;
            ushort4 b;
            b.x = f2bf(v.x); b.y = f2bf(v.y); b.z = f2bf(v.z); b.w = f2bf(v.w);
            *(ushort4*)&Xb[r * 256 + 4 * lane] = b;
            float ss = v.x * v.x + v.y * v.y + v.z * v.z + v.w * v.w;
            for (int off = 32; off; off >>= 1) ss += __shfl_down(ss, off);
            if (lane == 0) xsq[r] = ss;
        }
    }
    atomicAdd(&mu_sum[4 * lane + 0], cs0);
    atomicAdd(&mu_sum[4 * lane + 1], cs1);
    atomicAdd(&mu_sum[4 * lane + 2], cs2);
    atomicAdd(&mu_sum[4 * lane + 3], cs3);
}

// ---------------- covX accumulate via bf16 MFMA: acc += Xb^T Xb ----------------
// grid 256: bx&1 -> i-tile(128), (bx>>1)&1 -> j-tile, bx>>2 -> k-slice (64 x 1568)
__global__ __launch_bounds__(256, 2) void covx_mfma(const ushort* __restrict__ Xb,
                                                    float* __restrict__ acc_out) {
    __shared__ ushort XT[2][128][40];   // [half][d][k] pitch 40 (80B rows, 16B aligned)
    int t = threadIdx.x;
    int i0 = (blockIdx.x & 1) * 128;
    int j0 = ((blockIdx.x >> 1) & 1) * 128;
    int ks = (blockIdx.x >> 2) * 1568;
    int wv = t >> 6, lane = t & 63;
    int quad = lane >> 4, m16 = lane & 15;
    fx4 acc[16];
#pragma unroll
    for (int i = 0; i < 16; ++i) acc[i] = (fx4){0.f, 0.f, 0.f, 0.f};

    for (int kb = 0; kb < 1568; kb += 32) {
        __syncthreads();
#pragma unroll
        for (int s = 0; s < 4; ++s) {
            int id = t + 256 * s;           // 0..1023
            int kk = id & 31;
            int g  = (id >> 5) & 15;
            int h  = id >> 9;
            int kg = ks + kb + kk;
            int dbase = (h ? j0 : i0) + g * 8;
            union { uint4 u; ushort sh[8]; } cv;
            if (kg < NPTS) cv.u = *(const uint4*)&Xb[kg * 256 + dbase];
            else           cv.u = (uint4){0, 0, 0, 0};
#pragma unroll
            for (int jj = 0; jj < 8; ++jj) XT[h][g * 8 + jj][kk] = cv.sh[jj];
        }
        __syncthreads();
        bfx8 afr[2], bfr[8];
#pragma unroll
        for (int a = 0; a < 2; ++a)
            afr[a] = *(const bfx8*)&XT[0][(wv * 2 + a) * 16 + m16][quad * 8];
#pragma unroll
        for (int bj = 0; bj < 8; ++bj)
            bfr[bj] = *(const bfx8*)&XT[1][bj * 16 + m16][quad * 8];
#pragma unroll
        for (int a = 0; a < 2; ++a)
#pragma unroll
            for (int bj = 0; bj < 8; ++bj)
                acc[a * 8 + bj] = __builtin_amdgcn_mfma_f32_16x16x32_bf16(afr[a], bfr[bj], acc[a * 8 + bj], 0, 0, 0);
    }
#pragma unroll
    for (int a = 0; a < 2; ++a)
#pragma unroll
        for (int bj = 0; bj < 8; ++bj)
#pragma unroll
            for (int r = 0; r < 4; ++r) {
                int i = i0 + (wv * 2 + a) * 16 + quad * 4 + r;
                int j = j0 + bj * 16 + m16;
                atomicAdd(&acc_out[i * 256 + j], acc[a * 8 + bj][r]);
            }
}

// ---------------- grid barrier (monotone counter, device scope) ----------------
__device__ __forceinline__ void gbar(int* bar, int& target) {
    __syncthreads();
    if (threadIdx.x == 0) {
        target += NB;
        __threadfence();
        __hip_atomic_fetch_add(bar, 1, __ATOMIC_ACQ_REL, __HIP_MEMORY_SCOPE_AGENT);
        long spins = 0;
        while (__hip_atomic_load(bar, __ATOMIC_ACQUIRE, __HIP_MEMORY_SCOPE_AGENT) < target) {
            __builtin_amdgcn_s_sleep(2);
            if (++spins > (1L << 22)) break;   // failsafe: fail loud, not hung
        }
        __threadfence();
    }
    __syncthreads();
}

// ---------------- fp32 32x32 tile mm (K=256), As stored [k][i] ----------------
__device__ __forceinline__ void tile_mm(const float* __restrict__ A, const float* __restrict__ B,
                                        int i0, int j0, int transA,
                                        float (*As)[33], float (*Bs)[33],
                                        float acc[2][2], int t) {
    int tx = t & 15, ty = t >> 4;
    int lr = t >> 3, lc = (t & 7) * 4;
    acc[0][0] = acc[0][1] = acc[1][0] = acc[1][1] = 0.f;
    for (int kb = 0; kb < 256; kb += 32) {
        __syncthreads();
        if (transA) {
            float4 v = *(const float4*)&A[(kb + lr) * 256 + i0 + lc];
            *(float4*)&As[lr][lc] = v;
        } else {
            float4 v = *(const float4*)&A[(i0 + lr) * 256 + kb + lc];
            As[lc + 0][lr] = v.x; As[lc + 1][lr] = v.y; As[lc + 2][lr] = v.z; As[lc + 3][lr] = v.w;
        }
        {
            float4 v = *(const float4*)&B[(kb + lr) * 256 + j0 + lc];
            *(float4*)&Bs[lr][lc] = v;
        }
        __syncthreads();
#pragma unroll 8
        for (int kk = 0; kk < 32; ++kk) {
            float a0 = As[kk][2 * tx], a1 = As[kk][2 * tx + 1];
            float b0 = Bs[kk][2 * ty], b1 = Bs[kk][2 * ty + 1];
            acc[0][0] += a0 * b0; acc[0][1] += a0 * b1;
            acc[1][0] += a1 * b0; acc[1][1] += a1 * b1;
        }
    }
    __syncthreads();
}

// ---------------- persistent kernel: covxfin + T + stats + cov + G + NS + findist ----------------
__global__ __launch_bounds__(256, 1) void persist(const float* __restrict__ qb,
                                                  const float* __restrict__ W,
                                                  float* __restrict__ ws) {
    __shared__ float As[32][33];
    __shared__ float Bs[32][33];
    __shared__ float red[256];
    int b = blockIdx.x, t = threadIdx.x;
    int target = 0;
    int* bar = (int*)(ws + O_BAR);
    float* scal = ws + O_SCAL;
    float* covX = ws + O_COVX;
    float* Tm   = ws + O_TM;
    float* cov  = ws + O_COV;
    float* G    = ws + O_G;
    float* Pm   = ws + O_PM;
    float* muT  = ws + O_MUT;
    const float* mu_sum = ws + O_MUSUM;
    ushort* Tb = (ushort*)(ws + O_TB);
    const float invN = 1.0f / (float)NPTS;

    int i0 = (b >> 3) * 32, j0 = (b & 7) * 32;
    float acc[2][2];

    // phase -1: finalize covX (in place)
    for (int i = 0; i < 4; ++i) {
        int idx = b * 1024 + i * 256 + t;
        int r = idx >> 8, c = idx & 255;
        float v = covX[idx] * invN - (mu_sum[r] * invN) * (mu_sum[c] * invN) + ((r == c) ? 1e-4f : 0.f);
        covX[idx] = v;
        if (r == c) atomicAdd(&scal[SC_TRCX], v);
    }
    // phase 0: T = qb @ W  (+ bf16 copy)
    tile_mm(qb, W, i0, j0, 0, As, Bs, acc, t);
    {
        int tx = t & 15, ty = t >> 4;
#pragma unroll
        for (int ii = 0; ii < 2; ++ii)
#pragma unroll
            for (int jj = 0; jj < 2; ++jj) {
                int i = i0 + 2 * tx + ii, j = j0 + 2 * ty + jj;
                Tm[i * 256 + j] = acc[ii][jj];
                Tb[i * 256 + j] = f2bf(acc[ii][jj]);
            }
    }
    gbar(bar, target);
    // phase 1: mu_T + loss_mean
    {
        int wv = t >> 6, lane = t & 63;
        int d = b * 4 + wv;
        float s = Tm[lane * 256 + d] + Tm[(lane + 64) * 256 + d]
                + Tm[(lane + 128) * 256 + d] + Tm[(lane + 192) * 256 + d];
        for (int off = 32; off; off >>= 1) s += __shfl_down(s, off);
        if (lane == 0) {
            float mt = s * (1.0f / 256.0f);
            muT[d] = mt;
            float dm = mt - mu_sum[d] * invN;
            atomicAdd(&scal[SC_LM], dm * dm);
        }
    }
    gbar(bar, target);
    // phase 2: cov = T^T T /256 - muT muT^T + dI  (+trace)
    tile_mm(Tm, Tm, i0, j0, 1, As, Bs, acc, t);
    {
        int tx = t & 15, ty = t >> 4;
#pragma unroll
        for (int ii = 0; ii < 2; ++ii)
#pragma unroll
            for (int jj = 0; jj < 2; ++jj) {
                int i = i0 + 2 * tx + ii, j = j0 + 2 * ty + jj;
                float v = acc[ii][jj] * (1.0f / 256.0f) - muT[i] * muT[j] + ((i == j) ? 1e-4f : 0.f);
                cov[i * 256 + j] = v;
                if (i == j) atomicAdd(&scal[SC_TRCT], v);
            }
    }
    gbar(bar, target);
    // phase 3: G = cov @ covX  (+ frobenius^2)
    tile_mm(cov, covX, i0, j0, 0, As, Bs, acc, t);
    {
        int tx = t & 15, ty = t >> 4;
        float fr = 0.f;
#pragma unroll
        for (int ii = 0; ii < 2; ++ii)
#pragma unroll
            for (int jj = 0; jj < 2; ++jj) {
                int i = i0 + 2 * tx + ii, j = j0 + 2 * ty + jj;
                G[i * 256 + j] = acc[ii][jj];
                fr += acc[ii][jj] * acc[ii][jj];
            }
        red[t] = fr;
        __syncthreads();
        for (int s2 = 128; s2 > 0; s2 >>= 1) { if (t < s2) red[t] += red[t + s2]; __syncthreads(); }
        if (t == 0) atomicAdd(&scal[SC_FROB], red[0]);
    }
    gbar(bar, target);
    // phase 4: Y = G/||G||_F, Z = I
    {
        float invs = rsqrtf(scal[SC_FROB]);
        for (int i = 0; i < 4; ++i) {
            int idx = b * 1024 + i * 256 + t;
            (ws + O_Y0)[idx] = G[idx] * invs;
            (ws + O_Z0)[idx] = ((idx >> 8) == (idx & 255)) ? 1.0f : 0.0f;
        }
    }
    gbar(bar, target);
    // NS loop
    float* Yc = ws + O_Y0; float* Zc = ws + O_Z0;
    float* Yn = ws + O_Y1; float* Zn = ws + O_Z1;
    for (int it = 0; it < NS_ITERS; ++it) {
        // M = 1.5I - 0.5 * (Z @ Y)
        tile_mm(Zc, Yc, i0, j0, 0, As, Bs, acc, t);
        {
            int tx = t & 15, ty = t >> 4;
#pragma unroll
            for (int ii = 0; ii < 2; ++ii)
#pragma unroll
                for (int jj = 0; jj < 2; ++jj) {
                    int i = i0 + 2 * tx + ii, j = j0 + 2 * ty + jj;
                    Pm[i * 256 + j] = ((i == j) ? 1.5f : 0.f) - 0.5f * acc[ii][jj];
                }
        }
        gbar(bar, target);
        // Yn = Y @ M ; Zn = M @ Z
        tile_mm(Yc, Pm, i0, j0, 0, As, Bs, acc, t);
        {
            int tx = t & 15, ty = t >> 4;
#pragma unroll
            for (int ii = 0; ii < 2; ++ii)
#pragma unroll
                for (int jj = 0; jj < 2; ++jj)
                    Yn[(i0 + 2 * tx + ii) * 256 + j0 + 2 * ty + jj] = acc[ii][jj];
        }
        tile_mm(Pm, Zc, i0, j0, 0, As, Bs, acc, t);
        {
            int tx = t & 15, ty = t >> 4;
#pragma unroll
            for (int ii = 0; ii < 2; ++ii)
#pragma unroll
                for (int jj = 0; jj < 2; ++jj)
                    Zn[(i0 + 2 * tx + ii) * 256 + j0 + 2 * ty + jj] = acc[ii][jj];
        }
        gbar(bar, target);
        float* tp;
        tp = Yc; Yc = Yn; Yn = tp;
        tp = Zc; Zc = Zn; Zn = tp;
    }
    // findist (block 0)
    if (b == 0) {
        red[t] = Yc[t * 257];
        __syncthreads();
        for (int s2 = 128; s2 > 0; s2 >>= 1) { if (t < s2) red[t] += red[t + s2]; __syncthreads(); }
        if (t == 0) {
            float frobsq = scal[SC_FROB];
            float tr_sqrt = sqrtf(sqrtf(frobsq)) * red[0];
            float lc = scal[SC_TRCX] + scal[SC_TRCT] - 2.0f * tr_sqrt;
            scal[SC_LD] = fmaxf(0.0f, scal[SC_LM] + lc);
        }
    }
}

// ---------------- KNN: bf16 MFMA scores + per-block top-6 per query ----------------
// grid (782, 4): 128 points x 64 queries per block
__global__ __launch_bounds__(256, 2) void knn_mfma(const ushort* __restrict__ Xb,
                                                   const ushort* __restrict__ Tb,
                                                   const float* __restrict__ xsq,
                                                   float* __restrict__ ck, int* __restrict__ ci) {
    __shared__ ushort XT[4][130][8];     // [quad][p][j] : quad regions staggered by 8 banks
    __shared__ float kt[64][132];        // keys [query][point]
    __shared__ float t6k[6][256];
    __shared__ int   t6i[6][256];
    int t = threadIdx.x;
    int wv = t >> 6, lane = t & 63;
    int quad = lane >> 4, m16 = lane & 15;
    int p0 = blockIdx.x * 128, q0 = blockIdx.y * 64;

    fx4 acc[8];
#pragma unroll
    for (int i = 0; i < 8; ++i) acc[i] = (fx4){0.f, 0.f, 0.f, 0.f};

    for (int kb = 0; kb < 256; kb += 32) {
        __syncthreads();
#pragma unroll
        for (int s = 0; s < 2; ++s) {
            int id = t + 256 * s;        // 0..511
            int qd = id & 3;
            int p  = id >> 2;            // 0..127
            uint4 v = *(const uint4*)&Xb[(p0 + p) * 256 + kb + qd * 8];
            *(uint4*)&XT[qd][p][0] = v;
        }
        __syncthreads();
        bfx8 af = *(const bfx8*)&Tb[(q0 + wv * 16 + m16) * 256 + kb + quad * 8];
#pragma unroll
        for (int pt = 0; pt < 8; ++pt) {
            bfx8 bf_ = *(const bfx8*)&XT[quad][pt * 16 + m16][0];
            acc[pt] = __builtin_amdgcn_mfma_f32_16x16x32_bf16(af, bf_, acc[pt], 0, 0, 0);
        }
    }
    __syncthreads();
    // keys: C/D layout col=lane&15 (point), row=quad*4+r (query)
#pragma unroll
    for (int pt = 0; pt < 8; ++pt) {
        int p = pt * 16 + m16;
        float xs = (p0 + p < NPTS) ? xsq[p0 + p] : BIGF;
#pragma unroll
        for (int r = 0; r < 4; ++r) {
            int q = wv * 16 + quad * 4 + r;
            float key = (p0 + p < NPTS) ? (xs - 2.0f * acc[pt][r]) : BIGF;
            kt[q][p] = key;
        }
    }
    __syncthreads();
    // stage 1: (q, part) per thread, top-6 of 32
    {
        int q = t & 63, part = t >> 6;
#pragma unroll
        for (int s = 0; s < 6; ++s) { t6k[s][t] = BIGF; t6i[s][t] = 0x7fffffff; }
        float worst = BIGF; int wslot = 0;
        for (int i = 0; i < 32; ++i) {
            float key = kt[q][part * 32 + i];
            if (key < worst) {
                t6k[wslot][t] = key; t6i[wslot][t] = p0 + part * 32 + i;
                worst = t6k[0][t]; wslot = 0;
#pragma unroll
                for (int s = 1; s < 6; ++s)
                    if (t6k[s][t] > worst) { worst = t6k[s][t]; wslot = s; }
            }
        }
    }
    __syncthreads();
    // stage 2: merge 4 parts into column t (seeded with part 0), write top-6
    if (t < 64) {
        float worst = t6k[0][t]; int wslot = 0;
#pragma unroll
        for (int s = 1; s < 6; ++s)
            if (t6k[s][t] > worst) { worst = t6k[s][t]; wslot = s; }
        for (int part = 1; part < 4; ++part)
            for (int s2 = 0; s2 < 6; ++s2) {
                float key = t6k[s2][t + 64 * part];
                if (key < worst) {
                    t6k[wslot][t] = key; t6i[wslot][t] = t6i[s2][t + 64 * part];
                    worst = t6k[0][t]; wslot = 0;
#pragma unroll
                    for (int s = 1; s < 6; ++s)
                        if (t6k[s][t] > worst) { worst = t6k[s][t]; wslot = s; }
                }
            }
        int base = (q0 + t) * NCAND + blockIdx.x * 6;
#pragma unroll
        for (int s = 0; s < 6; ++s) { ck[base + s] = t6k[s][t]; ci[base + s] = t6i[s][t]; }
    }
}

// ---------------- global merge: top-32 candidates per query (one wave/query) ----------------
__global__ __launch_bounds__(64) void merge_kernel(const float* __restrict__ ck,
                                                   const int* __restrict__ ci,
                                                   int* __restrict__ cand32) {
    __shared__ float sk[8][64];
    __shared__ int   si[8][64];
    int q = blockIdx.x, lane = threadIdx.x;
#pragma unroll
    for (int s = 0; s < 8; ++s) { sk[s][lane] = BIGF; si[s][lane] = 0x7fffffff; }
    float worst = BIGF; int wslot = 0;
    for (int i = 0; i < 74; ++i) {
        int e = lane + 64 * i;
        if (e < NCAND) {
            float key = ck[q * NCAND + e];
            if (key < worst) {
                sk[wslot][lane] = key; si[wslot][lane] = ci[q * NCAND + e];
                worst = sk[0][lane]; wslot = 0;
#pragma unroll
                for (int s = 1; s < 8; ++s)
                    if (sk[s][lane] > worst) { worst = sk[s][lane]; wslot = s; }
            }
        }
    }
    for (int r = 0; r < 32; ++r) {
        float mk = sk[0][lane]; int mi = si[0][lane]; int ms = 0;
#pragma unroll
        for (int s = 1; s < 8; ++s) {
            float k2 = sk[s][lane]; int i2 = si[s][lane];
            if (k2 < mk || (k2 == mk && i2 < mi)) { mk = k2; mi = i2; ms = s; }
        }
        int ml = lane;
        for (int off = 32; off; off >>= 1) {
            float ok = __shfl_down(mk, off); int oi = __shfl_down(mi, off);
            int ol = __shfl_down(ml, off);   int os = __shfl_down(ms, off);
            if (ok < mk || (ok == mk && oi < mi)) { mk = ok; mi = oi; ml = ol; ms = os; }
        }
        mi = __shfl(mi, 0); ml = __shfl(ml, 0); ms = __shfl(ms, 0);
        if (lane == 0) cand32[q * 32 + r] = mi;
        if (lane == ml) { sk[ms][lane] = BIGF; si[ms][lane] = 0x7fffffff; }
    }
}

// ---------------- exact fp32 rerank of 32 cands -> top-16 + softmax ----------------
__global__ __launch_bounds__(256) void rerank(const float* __restrict__ Tm,
                                              const float* __restrict__ X,
                                              const int* __restrict__ cand32,
                                              int* __restrict__ post_idx,
                                              float* __restrict__ post_w) {
    __shared__ float Ts[256];
    __shared__ float d2s[32];
    __shared__ float l2sorted[16];
    __shared__ int   idxsorted[16];
    int q = blockIdx.x, t = threadIdx.x;
    Ts[t] = Tm[q * 256 + t];
    __syncthreads();
    int c = t >> 3, dl = t & 7;
    int idx = cand32[q * 32 + c];
    float s = 0.f;
    for (int i = 0; i < 32; ++i) {
        int d = dl + 8 * i;
        float df = Ts[d] - X[idx * 256 + d];
        s += df * df;
    }
    s += __shfl_down(s, 4, 8); s += __shfl_down(s, 2, 8); s += __shfl_down(s, 1, 8);
    if (dl == 0) d2s[c] = s;
    __syncthreads();
    if (t < 64) {
        float key = (t < 32) ? d2s[t] : BIGF;
        int   myi = (t < 32) ? cand32[q * 32 + t] : 0x7fffffff;
        bool used = false;
        for (int r = 0; r < 16; ++r) {
            float mk = used ? BIGF : key; int mi = myi; int ml = t;
            for (int off = 32; off; off >>= 1) {
                float ok = __shfl_down(mk, off); int oi = __shfl_down(mi, off); int ol = __shfl_down(ml, off);
                if (ok < mk || (ok == mk && oi < mi)) { mk = ok; mi = oi; ml = ol; }
            }
            mk = __shfl(mk, 0); mi = __shfl(mi, 0); ml = __shfl(ml, 0);
            if (t == ml) used = true;
            if (t == 0) { l2sorted[r] = mk; idxsorted[r] = mi; }
        }
    }
    __syncthreads();
    if (t < 16) {
        float w = expf(-10.0f * (l2sorted[t] - l2sorted[0]));   // -l2/TAU, max-sub
        float sum = w;
        for (int off = 8; off; off >>= 1) sum += __shfl_xor(sum, off, 16);
        post_w[q * 16 + t] = w / sum;
        post_idx[q * 16 + t] = idxsorted[t];
    }
}

// ---------------- KL per sample (exact reference semantics) ----------------
__global__ __launch_bounds__(256) void kl_kernel(const int* __restrict__ q_indices,
                                                 const int* __restrict__ pre_indices,
                                                 const float* __restrict__ pre_weights,
                                                 const int* __restrict__ post_idx,
                                                 const float* __restrict__ post_w,
                                                 float* __restrict__ scal) {
    int b = threadIdx.x;
    int qi = q_indices[b];
    int pid[16]; float pw[16]; int sid[16]; float sw[16];
    for (int k = 0; k < 16; ++k) {
        pid[k] = pre_indices[qi * 16 + k];
        pw[k]  = pre_weights[qi * 16 + k];
        sid[k] = post_idx[b * 16 + k];
        sw[k]  = post_w[b * 16 + k];
    }
    float psum = 0.f, qsum = 0.f, kl = 0.f;
    for (int pass = 0; pass < 2; ++pass) {
        for (int i = 0; i < 32; ++i) {
            int c = (i < 16) ? pid[i] : sid[i - 16];
            bool first = true;
            for (int jj = 0; jj < i; ++jj) {
                int cj = (jj < 16) ? pid[jj] : sid[jj - 16];
                if (cj == c) { first = false; break; }
            }
            if (!first) continue;
            float p = 0.f, q = 0.f;
            for (int k2 = 0; k2 < 16; ++k2) {
                if (pid[k2] == c) p += pw[k2];
                if (sid[k2] == c) q += sw[k2];
            }
            p = fmaxf(p, 1e-8f); q = fmaxf(q, 1e-8f);
            if (pass == 0) { psum += p; qsum += q; }
            else {
                float pn = p / psum, qn = q / qsum;
                kl += pn * (logf(pn) - logf(qn));
            }
        }
    }
    atomicAdd(&scal[SC_KNN], kl * (1.0f / 256.0f));
}

// ---------------- final assembly ----------------
__global__ void assemble_kernel(const float* __restrict__ scal, float* __restrict__ out) {
    if (threadIdx.x == 0) {
        float ld = scal[SC_LD], lk = scal[SC_KNN], reg = scal[SC_REG];
        out[0] = ld + lk + 1e-4f * 0.5f * reg;
        out[1] = ld;
        out[2] = lk;
    }
}

extern "C" void kernel_launch(void* const* d_in, const int* in_sizes, int n_in,
                              void* d_out, int out_size, void* d_ws, size_t ws_size,
                              hipStream_t stream) {
    (void)in_sizes; (void)n_in; (void)out_size; (void)ws_size;
    const float* X           = (const float*)d_in[0];
    const float* W           = (const float*)d_in[1];
    const float* q_batch     = (const float*)d_in[2];
    const float* pre_weights = (const float*)d_in[3];
    const int*   q_indices   = (const int*)d_in[4];
    const int*   pre_indices = (const int*)d_in[5];
    float* out = (float*)d_out;
    float* ws  = (float*)d_ws;

    float*  scal   = ws + O_SCAL;
    ushort* Xb     = (ushort*)(ws + O_XB);
    ushort* Tb     = (ushort*)(ws + O_TB);
    float*  xsq    = ws + O_XSQ;
    float*  ck     = ws + O_CK;
    int*    ci     = (int*)(ws + O_CI);
    int*    cand32 = (int*)(ws + O_CAND);
    int*    post_idx = (int*)(ws + O_POSTI);
    float*  post_w = ws + O_POSTW;

    zero_kernel<<<260, 256, 0, stream>>>(ws);
    reg_kernel<<<64, 256, 0, stream>>>(W, scal);
    statsconv<<<98, 256, 0, stream>>>(X, xsq, ws + O_MUSUM, Xb);
    covx_mfma<<<256, 256, 0, stream>>>(Xb, ws + O_COVX);
    persist<<<NB, 256, 0, stream>>>(q_batch, W, ws);
    knn_mfma<<<dim3(782, 4), 256, 0, stream>>>(Xb, Tb, xsq, ck, ci);
    merge_kernel<<<256, 64, 0, stream>>>(ck, ci, cand32);
    rerank<<<256, 256, 0, stream>>>(ws + O_TM, X, cand32, post_idx, post_w);
    kl_kernel<<<1, 256, 0, stream>>>(q_indices, pre_indices, pre_weights, post_idx, post_w, scal);
    assemble_kernel<<<1, 64, 0, stream>>>(scal, out);
}